// Round 4
// baseline (200.610 us; speedup 1.0000x reference)
//
#include <hip/hip_runtime.h>

// N0=N1=100000, K=16, D_MODEL=64, D_ATTN=32, H=4, dh_attn=8, dh_val=16
// KV = feats0 @ [Wk[:64]|Wv[:64]] + [bk|bv] -> f16 [n0][96]   (MFMA f16)
// Q  = feats1 @ Wq + bq                     -> f32 [n1][32]   (MFMA f16)
// attn: logit = q.K0[idx] + sum_c rel_c*(q.Wk3[c]) ; softmax (no max-sub, safe range)
//       out  = sum_j a_j V0[idx_j] + rbar @ Wv3    (softmax weights sum to 1)

using half8   = __attribute__((ext_vector_type(8))) _Float16;
using half4   = __attribute__((ext_vector_type(4))) _Float16;
using floatx4 = __attribute__((ext_vector_type(4))) float;

// ---------------------------------------------------------------------------
// Fused projection kernel. Blocks [0,nb0): KV tiles of feats0 (96 cols, f16 out,
// LDS-transposed coalesced stores). Blocks [nb0,nb0+nb1): Q tiles (32 cols, f32).
// A-frag (16x16x32): lane = l15 + 16*quad holds X[m0+l15][k=quad*8+j] (+32 for a1).
// B-frag: lane holds B[k=h*32+(lane>>4)*8+j][n=t*16+(lane&15)].
// C/D: col = lane&15, row = quad*4 + reg.
// ---------------------------------------------------------------------------
__global__ __launch_bounds__(256, 4) void proj_fused(
    const float* __restrict__ feats0, const float* __restrict__ feats1,
    const float* __restrict__ Wq, const float* __restrict__ bq,
    const float* __restrict__ Wk, const float* __restrict__ bk,
    const float* __restrict__ Wv, const float* __restrict__ bv,
    _Float16* __restrict__ KVh, float* __restrict__ Qf,
    int n0, int n1, int nb0)
{
    __shared__ __align__(16) _Float16 sFrag[6144];   // 12 KB B-frags
    __shared__ __align__(16) _Float16 sOut[6144];    // 12 KB transpose buffer (64 rows x 96)

    const int tid  = threadIdx.x;
    const int wave = tid >> 6;
    const int lane = tid & 63;
    const int l15  = lane & 15;
    const int quad = lane >> 4;

    if ((int)blockIdx.x < nb0) {
        // ---------------- KV tile ----------------
        const int rowBase = blockIdx.x * 64;
        for (int e = tid; e < 6144; e += 256) {
            int j = e & 7, ln = (e >> 3) & 63, h = (e >> 9) & 1, t = e >> 10;
            int k = h * 32 + ((ln >> 4) * 8) + j;
            int n = t * 16 + (ln & 15);
            float v = (n < 32) ? Wk[k * 32 + n] : Wv[k * 64 + (n - 32)];
            sFrag[e] = (_Float16)v;
        }
        __syncthreads();

        const int m0   = rowBase + wave * 16;
        const int row  = m0 + l15;
        const int rowc = (row < n0) ? row : (n0 - 1);
        const floatx4* X4 = (const floatx4*)(feats0 + (size_t)rowc * 64);
        floatx4 f0 = X4[quad * 2 + 0], f1 = X4[quad * 2 + 1];
        floatx4 f2 = X4[quad * 2 + 8], f3 = X4[quad * 2 + 9];
        half8 a0, a1;
        a0[0]=(_Float16)f0.x; a0[1]=(_Float16)f0.y; a0[2]=(_Float16)f0.z; a0[3]=(_Float16)f0.w;
        a0[4]=(_Float16)f1.x; a0[5]=(_Float16)f1.y; a0[6]=(_Float16)f1.z; a0[7]=(_Float16)f1.w;
        a1[0]=(_Float16)f2.x; a1[1]=(_Float16)f2.y; a1[2]=(_Float16)f2.z; a1[3]=(_Float16)f2.w;
        a1[4]=(_Float16)f3.x; a1[5]=(_Float16)f3.y; a1[6]=(_Float16)f3.z; a1[7]=(_Float16)f3.w;

        const half8* bf = (const half8*)sFrag;
        floatx4 acc[6];
        #pragma unroll
        for (int t = 0; t < 6; t++) {
            int n = t * 16 + l15;
            float bb = (n < 32) ? bk[n] : bv[n - 32];
            acc[t] = (floatx4){bb, bb, bb, bb};
        }
        #pragma unroll
        for (int t = 0; t < 6; t++) {
            acc[t] = __builtin_amdgcn_mfma_f32_16x16x32_f16(a0, bf[(t*2+0)*64 + lane], acc[t], 0,0,0);
            acc[t] = __builtin_amdgcn_mfma_f32_16x16x32_f16(a1, bf[(t*2+1)*64 + lane], acc[t], 0,0,0);
        }

        // transpose through LDS -> fully coalesced 16B stores
        // BUGFIX (r3): include wave*16 row offset — each wave owns rows [wave*16, wave*16+16)
        #pragma unroll
        for (int t = 0; t < 6; t++)
            #pragma unroll
            for (int r = 0; r < 4; r++)
                sOut[(wave * 16 + quad * 4 + r) * 96 + t * 16 + l15] = (_Float16)acc[t][r];
        __syncthreads();

        const half8* so8 = (const half8*)sOut;
        half8* dst = (half8*)(KVh + (size_t)rowBase * 96);
        for (int c = tid; c < 768; c += 256) {        // 12 chunks of 16B per row
            int r = c / 12;
            if (rowBase + r < n0) dst[c] = so8[c];
        }
    } else {
        // ---------------- Q tile ----------------
        const int rowBase = ((int)blockIdx.x - nb0) * 64;
        for (int e = tid; e < 2048; e += 256) {
            int j = e & 7, ln = (e >> 3) & 63, h = (e >> 9) & 1, t = e >> 10;
            int k = h * 32 + ((ln >> 4) * 8) + j;
            int n = t * 16 + (ln & 15);
            sFrag[e] = (_Float16)Wq[k * 32 + n];
        }
        __syncthreads();

        const int m0   = rowBase + wave * 16;
        const int row  = m0 + l15;
        const int rowc = (row < n1) ? row : (n1 - 1);
        const floatx4* X4 = (const floatx4*)(feats1 + (size_t)rowc * 64);
        floatx4 f0 = X4[quad * 2 + 0], f1 = X4[quad * 2 + 1];
        floatx4 f2 = X4[quad * 2 + 8], f3 = X4[quad * 2 + 9];
        half8 a0, a1;
        a0[0]=(_Float16)f0.x; a0[1]=(_Float16)f0.y; a0[2]=(_Float16)f0.z; a0[3]=(_Float16)f0.w;
        a0[4]=(_Float16)f1.x; a0[5]=(_Float16)f1.y; a0[6]=(_Float16)f1.z; a0[7]=(_Float16)f1.w;
        a1[0]=(_Float16)f2.x; a1[1]=(_Float16)f2.y; a1[2]=(_Float16)f2.z; a1[3]=(_Float16)f2.w;
        a1[4]=(_Float16)f3.x; a1[5]=(_Float16)f3.y; a1[6]=(_Float16)f3.z; a1[7]=(_Float16)f3.w;

        const half8* bf = (const half8*)sFrag;
        floatx4 acc[2];
        #pragma unroll
        for (int t = 0; t < 2; t++) {
            float bb = bq[t * 16 + l15];
            acc[t] = (floatx4){bb, bb, bb, bb};
        }
        #pragma unroll
        for (int t = 0; t < 2; t++) {
            acc[t] = __builtin_amdgcn_mfma_f32_16x16x32_f16(a0, bf[(t*2+0)*64 + lane], acc[t], 0,0,0);
            acc[t] = __builtin_amdgcn_mfma_f32_16x16x32_f16(a1, bf[(t*2+1)*64 + lane], acc[t], 0,0,0);
        }
        #pragma unroll
        for (int t = 0; t < 2; t++)
            #pragma unroll
            for (int r = 0; r < 4; r++) {
                int ro = m0 + quad * 4 + r;
                if (ro < n1) Qf[(size_t)ro * 32 + t * 16 + l15] = acc[t][r];
            }
    }
}

// ---------------------------------------------------------------------------
// Attention: 16 lanes/point, 16 points/block (4 points per wave -> all intra-
// point comms are wave-synchronous shfl/LDS).
// ---------------------------------------------------------------------------
__global__ __launch_bounds__(256, 4) void attn_kernel(
    const float* __restrict__ coords0, const float* __restrict__ coords1,
    const int*   __restrict__ knn,
    const float* __restrict__ Qf, const _Float16* __restrict__ KVh,
    const float* __restrict__ Wk, const float* __restrict__ Wv,
    float* __restrict__ out, float* __restrict__ outIdx, int n1)
{
    __shared__ __align__(16) float sQ[16][36];   // pad 36: conflict-free f4 reads
    __shared__ float sWk3[3][32];
    __shared__ float sWv3[3][64];
    __shared__ float sAttn[16][4][18];
    __shared__ float sRel[16][16][3];
    __shared__ int   sIdx[16][16];

    const int tid = threadIdx.x;
    // BUGFIX (r3): cover all 96 + 192 = 288 staged floats (tid only spans 256)
    for (int e = tid; e < 288; e += 256) {
        if (e < 96) ((float*)sWk3)[e] = Wk[2048 + e];
        else        ((float*)sWv3)[e - 96] = Wv[4096 + (e - 96)];
    }
    if (tid < 128) {                      // stage Q rows for the block's 16 points
        int pt = tid >> 3, c4 = tid & 7;
        int r = blockIdx.x * 16 + pt;
        if (r >= n1) r = n1 - 1;
        ((floatx4*)&sQ[pt][0])[c4] = ((const floatx4*)Qf)[(size_t)r * 8 + c4];
    }
    __syncthreads();

    const int p = tid >> 4;
    const int j = tid & 15;
    const int n = blockIdx.x * 16 + p;
    const bool valid = (n < n1);
    const int nc = valid ? n : (n1 - 1);

    // ---- Phase 1: neighbor-parallel logits + softmax ----
    const int idx = knn[nc * 16 + j];
    const half8* kr = (const half8*)(KVh + (size_t)idx * 96);
    half8 k8[4];
    #pragma unroll
    for (int h = 0; h < 4; h++) k8[h] = kr[h];          // hoisted 4x16B gather

    const float r0 = coords0[idx * 3 + 0] - coords1[nc * 3 + 0];
    const float r1 = coords0[idx * 3 + 1] - coords1[nc * 3 + 1];
    const float r2 = coords0[idx * 3 + 2] - coords1[nc * 3 + 2];

    // t[c][h] = q_h . Wk3[c, h*8:+8]  — lane c*4+h computes one, then broadcast
    float t_own = 0.f;
    if (j < 12) {
        int c = j >> 2, h = j & 3;
        #pragma unroll
        for (int i = 0; i < 8; i++)
            t_own = fmaf(sWk3[c][h * 8 + i], sQ[p][h * 8 + i], t_own);
    }
    float tt[3][4];
    #pragma unroll
    for (int c = 0; c < 3; c++)
        #pragma unroll
        for (int h = 0; h < 4; h++)
            tt[c][h] = __shfl(t_own, c * 4 + h, 16);

    const float scale = 0.35355339059327373f;  // 1/sqrt(8)
    #pragma unroll
    for (int h = 0; h < 4; h++) {
        floatx4 q0 = ((const floatx4*)&sQ[p][0])[h * 2 + 0];
        floatx4 q1 = ((const floatx4*)&sQ[p][0])[h * 2 + 1];
        float acc = r0 * tt[0][h] + r1 * tt[1][h] + r2 * tt[2][h];
        acc = fmaf(q0.x, (float)k8[h][0], acc);
        acc = fmaf(q0.y, (float)k8[h][1], acc);
        acc = fmaf(q0.z, (float)k8[h][2], acc);
        acc = fmaf(q0.w, (float)k8[h][3], acc);
        acc = fmaf(q1.x, (float)k8[h][4], acc);
        acc = fmaf(q1.y, (float)k8[h][5], acc);
        acc = fmaf(q1.z, (float)k8[h][6], acc);
        acc = fmaf(q1.w, (float)k8[h][7], acc);
        // softmax without max-sub: |logit*scale| <~ 8 -> f32 exp safe
        float e = __expf(acc * scale);
        float s = e;
        s += __shfl_xor(s, 1, 16);
        s += __shfl_xor(s, 2, 16);
        s += __shfl_xor(s, 4, 16);
        s += __shfl_xor(s, 8, 16);
        sAttn[p][h][j] = e * __builtin_amdgcn_rcpf(s);
    }
    sRel[p][j][0] = r0; sRel[p][j][1] = r1; sRel[p][j][2] = r2;
    sIdx[p][j] = idx;
    if (valid) outIdx[n * 16 + j] = (float)idx;

    __syncthreads();

    // ---- Phase 2: row-pair dim-parallel V gather (8x16B hoisted loads/lane) ----
    const int g = j & 7;          // dim group: dims [8g, 8g+8)
    const int hf = j >> 3;        // which row of each pair
    const int h = g >> 1;         // head owning those dims

    int   iv[8];
    float av[8];
    #pragma unroll
    for (int s = 0; s < 8; s++) {
        iv[s] = sIdx[p][2 * s + hf];
        av[s] = sAttn[p][h][2 * s + hf];
    }
    half8 v8[8];
    #pragma unroll
    for (int s = 0; s < 8; s++)
        v8[s] = *(const half8*)(KVh + (size_t)iv[s] * 96 + 32 + g * 8);

    float acc8[8] = {0,0,0,0,0,0,0,0};
    float rb0 = 0.f, rb1 = 0.f, rb2 = 0.f;
    #pragma unroll
    for (int s = 0; s < 8; s++) {
        float a = av[s];
        #pragma unroll
        for (int i = 0; i < 8; i++)
            acc8[i] = fmaf(a, (float)v8[s][i], acc8[i]);
        rb0 = fmaf(a, sRel[p][2 * s + hf][0], rb0);
        rb1 = fmaf(a, sRel[p][2 * s + hf][1], rb1);
        rb2 = fmaf(a, sRel[p][2 * s + hf][2], rb2);
    }
    #pragma unroll
    for (int i = 0; i < 8; i++) acc8[i] += __shfl_xor(acc8[i], 8, 16);
    rb0 += __shfl_xor(rb0, 8, 16);
    rb1 += __shfl_xor(rb1, 8, 16);
    rb2 += __shfl_xor(rb2, 8, 16);

    #pragma unroll
    for (int i = 0; i < 8; i++)
        acc8[i] += rb0 * sWv3[0][8 * g + i] + rb1 * sWv3[1][8 * g + i] + rb2 * sWv3[2][8 * g + i];

    if (valid) {
        floatx4 st = { acc8[hf * 4 + 0], acc8[hf * 4 + 1], acc8[hf * 4 + 2], acc8[hf * 4 + 3] };
        ((floatx4*)out)[(size_t)n * 16 + g * 2 + hf] = st;
    }
}

// ---------------------------------------------------------------------------
extern "C" void kernel_launch(void* const* d_in, const int* in_sizes, int n_in,
                              void* d_out, int out_size, void* d_ws, size_t ws_size,
                              hipStream_t stream) {
    const float* coords0 = (const float*)d_in[0];
    const float* coords1 = (const float*)d_in[1];
    const float* feats0  = (const float*)d_in[2];
    const float* feats1  = (const float*)d_in[3];
    const int*   knn     = (const int*)d_in[4];
    const float* Wq      = (const float*)d_in[5];
    const float* bq      = (const float*)d_in[6];
    const float* Wk      = (const float*)d_in[7];
    const float* bk      = (const float*)d_in[8];
    const float* Wv      = (const float*)d_in[9];
    const float* bv      = (const float*)d_in[10];

    const int n0 = in_sizes[0] / 3;
    const int n1 = in_sizes[1] / 3;

    char* ws = (char*)d_ws;
    _Float16* KVh = (_Float16*)ws;                         // [n0][96] f16
    float*    Qf  = (float*)(ws + (size_t)n0 * 96 * 2);    // [n1][32] f32

    float* out    = (float*)d_out;                         // [n1,64]
    float* outIdx = out + (size_t)n1 * 64;                 // [1,n1,16] as float

    const int nb0 = (n0 + 63) / 64;
    const int nb1 = (n1 + 63) / 64;

    proj_fused<<<nb0 + nb1, 256, 0, stream>>>(feats0, feats1, Wq, bq, Wk, bk, Wv, bv,
                                              KVh, Qf, n0, n1, nb0);
    attn_kernel<<<(n1 + 15) / 16, 256, 0, stream>>>(coords0, coords1, knn,
                                                    Qf, KVh, Wk, Wv, out, outIdx, n1);
}

// Round 5
// 191.152 us; speedup vs baseline: 1.0495x; 1.0495x over previous
//
#include <hip/hip_runtime.h>

// N0=N1=100000, K=16, D_MODEL=64, D_ATTN=32, H=4, dh_attn=8, dh_val=16
// KV = feats0 @ [Wk[:64]|Wv[:64]] + [bk|bv] -> f16 [n0][96]   (MFMA f16)
// Q  = feats1 @ Wq + bq                     -> f32 [n1][32]   (MFMA f16)
// attn: logit = q.K0[idx] + sum_c rel_c*(q.Wk3[c]) ; softmax (no max-sub, safe range)
//       out  = sum_j a_j V0[idx_j] + rbar @ Wv3    (softmax weights sum to 1)
// r5: attn is wave-synchronous — no mid-kernel __syncthreads, all cross-lane
//     exchange via __shfl, so all 12 gathers/lane are simultaneously in flight.

using half8   = __attribute__((ext_vector_type(8))) _Float16;
using floatx4 = __attribute__((ext_vector_type(4))) float;

// ---------------------------------------------------------------------------
// Fused projection kernel (unchanged from r4 — working, ~20 us).
// Blocks [0,nb0): KV tiles of feats0. Blocks [nb0,nb0+nb1): Q tiles.
// ---------------------------------------------------------------------------
__global__ __launch_bounds__(256, 4) void proj_fused(
    const float* __restrict__ feats0, const float* __restrict__ feats1,
    const float* __restrict__ Wq, const float* __restrict__ bq,
    const float* __restrict__ Wk, const float* __restrict__ bk,
    const float* __restrict__ Wv, const float* __restrict__ bv,
    _Float16* __restrict__ KVh, float* __restrict__ Qf,
    int n0, int n1, int nb0)
{
    __shared__ __align__(16) _Float16 sFrag[6144];
    __shared__ __align__(16) _Float16 sOut[6144];

    const int tid  = threadIdx.x;
    const int wave = tid >> 6;
    const int lane = tid & 63;
    const int l15  = lane & 15;
    const int quad = lane >> 4;

    if ((int)blockIdx.x < nb0) {
        const int rowBase = blockIdx.x * 64;
        for (int e = tid; e < 6144; e += 256) {
            int j = e & 7, ln = (e >> 3) & 63, h = (e >> 9) & 1, t = e >> 10;
            int k = h * 32 + ((ln >> 4) * 8) + j;
            int n = t * 16 + (ln & 15);
            float v = (n < 32) ? Wk[k * 32 + n] : Wv[k * 64 + (n - 32)];
            sFrag[e] = (_Float16)v;
        }
        __syncthreads();

        const int m0   = rowBase + wave * 16;
        const int row  = m0 + l15;
        const int rowc = (row < n0) ? row : (n0 - 1);
        const floatx4* X4 = (const floatx4*)(feats0 + (size_t)rowc * 64);
        floatx4 f0 = X4[quad * 2 + 0], f1 = X4[quad * 2 + 1];
        floatx4 f2 = X4[quad * 2 + 8], f3 = X4[quad * 2 + 9];
        half8 a0, a1;
        a0[0]=(_Float16)f0.x; a0[1]=(_Float16)f0.y; a0[2]=(_Float16)f0.z; a0[3]=(_Float16)f0.w;
        a0[4]=(_Float16)f1.x; a0[5]=(_Float16)f1.y; a0[6]=(_Float16)f1.z; a0[7]=(_Float16)f1.w;
        a1[0]=(_Float16)f2.x; a1[1]=(_Float16)f2.y; a1[2]=(_Float16)f2.z; a1[3]=(_Float16)f2.w;
        a1[4]=(_Float16)f3.x; a1[5]=(_Float16)f3.y; a1[6]=(_Float16)f3.z; a1[7]=(_Float16)f3.w;

        const half8* bf = (const half8*)sFrag;
        floatx4 acc[6];
        #pragma unroll
        for (int t = 0; t < 6; t++) {
            int n = t * 16 + l15;
            float bb = (n < 32) ? bk[n] : bv[n - 32];
            acc[t] = (floatx4){bb, bb, bb, bb};
        }
        #pragma unroll
        for (int t = 0; t < 6; t++) {
            acc[t] = __builtin_amdgcn_mfma_f32_16x16x32_f16(a0, bf[(t*2+0)*64 + lane], acc[t], 0,0,0);
            acc[t] = __builtin_amdgcn_mfma_f32_16x16x32_f16(a1, bf[(t*2+1)*64 + lane], acc[t], 0,0,0);
        }

        #pragma unroll
        for (int t = 0; t < 6; t++)
            #pragma unroll
            for (int r = 0; r < 4; r++)
                sOut[(wave * 16 + quad * 4 + r) * 96 + t * 16 + l15] = (_Float16)acc[t][r];
        __syncthreads();

        const half8* so8 = (const half8*)sOut;
        half8* dst = (half8*)(KVh + (size_t)rowBase * 96);
        for (int c = tid; c < 768; c += 256) {
            int r = c / 12;
            if (rowBase + r < n0) dst[c] = so8[c];
        }
    } else {
        const int rowBase = ((int)blockIdx.x - nb0) * 64;
        for (int e = tid; e < 2048; e += 256) {
            int j = e & 7, ln = (e >> 3) & 63, h = (e >> 9) & 1, t = e >> 10;
            int k = h * 32 + ((ln >> 4) * 8) + j;
            int n = t * 16 + (ln & 15);
            sFrag[e] = (_Float16)Wq[k * 32 + n];
        }
        __syncthreads();

        const int m0   = rowBase + wave * 16;
        const int row  = m0 + l15;
        const int rowc = (row < n1) ? row : (n1 - 1);
        const floatx4* X4 = (const floatx4*)(feats1 + (size_t)rowc * 64);
        floatx4 f0 = X4[quad * 2 + 0], f1 = X4[quad * 2 + 1];
        floatx4 f2 = X4[quad * 2 + 8], f3 = X4[quad * 2 + 9];
        half8 a0, a1;
        a0[0]=(_Float16)f0.x; a0[1]=(_Float16)f0.y; a0[2]=(_Float16)f0.z; a0[3]=(_Float16)f0.w;
        a0[4]=(_Float16)f1.x; a0[5]=(_Float16)f1.y; a0[6]=(_Float16)f1.z; a0[7]=(_Float16)f1.w;
        a1[0]=(_Float16)f2.x; a1[1]=(_Float16)f2.y; a1[2]=(_Float16)f2.z; a1[3]=(_Float16)f2.w;
        a1[4]=(_Float16)f3.x; a1[5]=(_Float16)f3.y; a1[6]=(_Float16)f3.z; a1[7]=(_Float16)f3.w;

        const half8* bf = (const half8*)sFrag;
        floatx4 acc[2];
        #pragma unroll
        for (int t = 0; t < 2; t++) {
            float bb = bq[t * 16 + l15];
            acc[t] = (floatx4){bb, bb, bb, bb};
        }
        #pragma unroll
        for (int t = 0; t < 2; t++) {
            acc[t] = __builtin_amdgcn_mfma_f32_16x16x32_f16(a0, bf[(t*2+0)*64 + lane], acc[t], 0,0,0);
            acc[t] = __builtin_amdgcn_mfma_f32_16x16x32_f16(a1, bf[(t*2+1)*64 + lane], acc[t], 0,0,0);
        }
        #pragma unroll
        for (int t = 0; t < 2; t++)
            #pragma unroll
            for (int r = 0; r < 4; r++) {
                int ro = m0 + quad * 4 + r;
                if (ro < n1) Qf[(size_t)ro * 32 + t * 16 + l15] = acc[t][r];
            }
    }
}

// ---------------------------------------------------------------------------
// Attention, wave-synchronous. 16 lanes/point, 4 points/wave, 16 points/block.
// One __syncthreads (initial staging of Q + Wk3/Wv3); everything else shfl.
// ---------------------------------------------------------------------------
__global__ __launch_bounds__(256, 4) void attn_kernel(
    const float* __restrict__ coords0, const float* __restrict__ coords1,
    const int*   __restrict__ knn,
    const float* __restrict__ Qf, const _Float16* __restrict__ KVh,
    const float* __restrict__ Wk, const float* __restrict__ Wv,
    float* __restrict__ out, float* __restrict__ outIdx, int n1)
{
    __shared__ __align__(16) float sQ[16][36];   // pad 36: conflict-free f4 reads
    __shared__ float sWk3[3][32];
    __shared__ float sWv3[3][64];

    const int tid = threadIdx.x;
    for (int e = tid; e < 288; e += 256) {
        if (e < 96) ((float*)sWk3)[e] = Wk[2048 + e];
        else        ((float*)sWv3)[e - 96] = Wv[4096 + (e - 96)];
    }
    if (tid < 128) {                      // stage Q rows for the block's 16 points
        int pt = tid >> 3, c4 = tid & 7;
        int r = blockIdx.x * 16 + pt;
        if (r >= n1) r = n1 - 1;
        ((floatx4*)&sQ[pt][0])[c4] = ((const floatx4*)Qf)[(size_t)r * 8 + c4];
    }
    __syncthreads();   // the only block barrier

    const int p = tid >> 4;          // point in block (0..15); lanes of p share a wave
    const int j = tid & 15;          // lane within point = neighbor id
    const int n = blockIdx.x * 16 + p;
    const bool valid = (n < n1);
    const int nc = valid ? n : (n1 - 1);

    // ---- issue ALL gathers up front ----
    const int idx = knn[nc * 16 + j];                       // own neighbor index

    const half8* kr = (const half8*)(KVh + (size_t)idx * 96);
    half8 k8_0 = kr[0], k8_1 = kr[1], k8_2 = kr[2], k8_3 = kr[3];   // K row 64B

    const float r0 = coords0[idx * 3 + 0] - coords1[nc * 3 + 0];
    const float r1 = coords0[idx * 3 + 1] - coords1[nc * 3 + 1];
    const float r2 = coords0[idx * 3 + 2] - coords1[nc * 3 + 2];

    const int g  = j & 7;            // dim group for phase 2: dims [8g, 8g+8)
    const int hf = j >> 3;           // row of each neighbor pair
    const int h  = g >> 1;           // head owning dims [8g, 8g+8)

    int vIdx[8];
    #pragma unroll
    for (int s = 0; s < 8; s++)
        vIdx[s] = __shfl(idx, 2 * s + hf, 16);              // neighbor 2s+hf's index
    half8 v8[8];
    #pragma unroll
    for (int s = 0; s < 8; s++)
        v8[s] = *(const half8*)(KVh + (size_t)vIdx[s] * 96 + 32 + g * 8);  // V 16B

    // ---- logits: q.K + rel.(q@Wk3) ----
    // t[c][h2] = q_h2 . Wk3[c, h2*8:+8], computed by lane c*4+h2 then broadcast
    float t_own = 0.f;
    if (j < 12) {
        int c = j >> 2, h2 = j & 3;
        #pragma unroll
        for (int i = 0; i < 8; i++)
            t_own = fmaf(sWk3[c][h2 * 8 + i], sQ[p][h2 * 8 + i], t_own);
    }
    float tt[3][4];
    #pragma unroll
    for (int c = 0; c < 3; c++)
        #pragma unroll
        for (int h2 = 0; h2 < 4; h2++)
            tt[c][h2] = __shfl(t_own, c * 4 + h2, 16);

    const float scale = 0.35355339059327373f;  // 1/sqrt(8)
    float a0, a1, a2, a3;                       // own neighbor's attn, all 4 heads
    {
        half8 k8[4] = {k8_0, k8_1, k8_2, k8_3};
        float av[4];
        #pragma unroll
        for (int h2 = 0; h2 < 4; h2++) {
            floatx4 q0 = ((const floatx4*)&sQ[p][0])[h2 * 2 + 0];
            floatx4 q1 = ((const floatx4*)&sQ[p][0])[h2 * 2 + 1];
            float acc = r0 * tt[0][h2] + r1 * tt[1][h2] + r2 * tt[2][h2];
            acc = fmaf(q0.x, (float)k8[h2][0], acc);
            acc = fmaf(q0.y, (float)k8[h2][1], acc);
            acc = fmaf(q0.z, (float)k8[h2][2], acc);
            acc = fmaf(q0.w, (float)k8[h2][3], acc);
            acc = fmaf(q1.x, (float)k8[h2][4], acc);
            acc = fmaf(q1.y, (float)k8[h2][5], acc);
            acc = fmaf(q1.z, (float)k8[h2][6], acc);
            acc = fmaf(q1.w, (float)k8[h2][7], acc);
            float e = __expf(acc * scale);      // |logit*scale| small: no max-sub
            float s = e;
            s += __shfl_xor(s, 1, 16);
            s += __shfl_xor(s, 2, 16);
            s += __shfl_xor(s, 4, 16);
            s += __shfl_xor(s, 8, 16);
            av[h2] = e * __builtin_amdgcn_rcpf(s);
        }
        a0 = av[0]; a1 = av[1]; a2 = av[2]; a3 = av[3];
    }

    if (valid) outIdx[n * 16 + j] = (float)idx;

    // ---- phase 2: weighted V sum, all exchange via shfl ----
    float acc8[8] = {0,0,0,0,0,0,0,0};
    float rb0 = 0.f, rb1 = 0.f, rb2 = 0.f;
    #pragma unroll
    for (int s = 0; s < 8; s++) {
        const int src = 2 * s + hf;
        float t0 = __shfl(a0, src, 16);
        float t1 = __shfl(a1, src, 16);
        float t2 = __shfl(a2, src, 16);
        float t3 = __shfl(a3, src, 16);
        float av = (h == 0) ? t0 : (h == 1) ? t1 : (h == 2) ? t2 : t3;
        float sr0 = __shfl(r0, src, 16);
        float sr1 = __shfl(r1, src, 16);
        float sr2 = __shfl(r2, src, 16);
        #pragma unroll
        for (int i = 0; i < 8; i++)
            acc8[i] = fmaf(av, (float)v8[s][i], acc8[i]);
        rb0 = fmaf(av, sr0, rb0);
        rb1 = fmaf(av, sr1, rb1);
        rb2 = fmaf(av, sr2, rb2);
    }
    #pragma unroll
    for (int i = 0; i < 8; i++) acc8[i] += __shfl_xor(acc8[i], 8, 16);
    rb0 += __shfl_xor(rb0, 8, 16);
    rb1 += __shfl_xor(rb1, 8, 16);
    rb2 += __shfl_xor(rb2, 8, 16);

    #pragma unroll
    for (int i = 0; i < 8; i++)
        acc8[i] += rb0 * sWv3[0][8 * g + i] + rb1 * sWv3[1][8 * g + i] + rb2 * sWv3[2][8 * g + i];

    if (valid) {
        floatx4 st = { acc8[hf * 4 + 0], acc8[hf * 4 + 1], acc8[hf * 4 + 2], acc8[hf * 4 + 3] };
        ((floatx4*)out)[(size_t)n * 16 + g * 2 + hf] = st;
    }
}

// ---------------------------------------------------------------------------
extern "C" void kernel_launch(void* const* d_in, const int* in_sizes, int n_in,
                              void* d_out, int out_size, void* d_ws, size_t ws_size,
                              hipStream_t stream) {
    const float* coords0 = (const float*)d_in[0];
    const float* coords1 = (const float*)d_in[1];
    const float* feats0  = (const float*)d_in[2];
    const float* feats1  = (const float*)d_in[3];
    const int*   knn     = (const int*)d_in[4];
    const float* Wq      = (const float*)d_in[5];
    const float* bq      = (const float*)d_in[6];
    const float* Wk      = (const float*)d_in[7];
    const float* bk      = (const float*)d_in[8];
    const float* Wv      = (const float*)d_in[9];
    const float* bv      = (const float*)d_in[10];

    const int n0 = in_sizes[0] / 3;
    const int n1 = in_sizes[1] / 3;

    char* ws = (char*)d_ws;
    _Float16* KVh = (_Float16*)ws;                         // [n0][96] f16
    float*    Qf  = (float*)(ws + (size_t)n0 * 96 * 2);    // [n1][32] f32

    float* out    = (float*)d_out;                         // [n1,64]
    float* outIdx = out + (size_t)n1 * 64;                 // [1,n1,16] as float

    const int nb0 = (n0 + 63) / 64;
    const int nb1 = (n1 + 63) / 64;

    proj_fused<<<nb0 + nb1, 256, 0, stream>>>(feats0, feats1, Wq, bq, Wk, bk, Wv, bv,
                                              KVh, Qf, n0, n1, nb0);
    attn_kernel<<<(n1 + 15) / 16, 256, 0, stream>>>(coords0, coords1, knn,
                                                    Qf, KVh, Wk, Wv, out, outIdx, n1);
}